// Round 6
// baseline (49.552 us; speedup 1.0000x reference)
//
#include <hip/hip_runtime.h>

// Batched Gram-Schmidt, memory-system-focused round:
// - PLAIN (writeback) stores: output stays L2/InfinityCache-resident across
//   graph replays (working set 198MB < 256MB MALL). R2-R5's nontemporal
//   stores forced 98MB of HBM writes per replay.
// - 2 batches per 192-thread block, ALL 16 loads issued before any compute:
//   batch-B's memory latency hides under batch-A's reduction/compute chains.
// - R4 phase structure otherwise (empirically fastest): batched per-phase
//   dots, wave shuffle reduce + tiny LDS cross-wave combine, fused multi-axpy,
//   normalization deferred to the store.

#define S_VECS 8
#define D_DIM 768
#define CHUNKS 192  // float4 chunks per vector

typedef float f32x4 __attribute__((ext_vector_type(4)));

__device__ __forceinline__ float wave_reduce_sum(float x) {
#pragma unroll
    for (int off = 32; off >= 1; off >>= 1)
        x += __shfl_xor(x, off, 64);
    return x;
}

__device__ __forceinline__ void process_store(float (&v)[S_VECS][4],
                                              float (*red)[S_VECS][3],
                                              int wave, int lane, int w1, int w2,
                                              float* __restrict__ out,
                                              size_t b, int chunk) {
    float inv_n[S_VECS];

#pragma unroll
    for (int i = 1; i < S_VECS; ++i) {
        const int p = i & 1;
        float d[S_VECS];
#pragma unroll
        for (int j = 0; j < S_VECS; ++j) {
            if (j < i) {
                float acc = 0.f;
#pragma unroll
                for (int e = 0; e < 4; ++e) acc += v[i][e] * v[j][e];
                d[j] = acc;
            }
        }
        float self = 0.f;
#pragma unroll
        for (int e = 0; e < 4; ++e) self += v[i - 1][e] * v[i - 1][e];

#pragma unroll
        for (int j = 0; j < S_VECS; ++j) {
            if (j < i) d[j] = wave_reduce_sum(d[j]);
        }
        self = wave_reduce_sum(self);

        if (lane == 0) {
#pragma unroll
            for (int j = 0; j < S_VECS; ++j) {
                if (j < i) red[p][j][wave] = d[j];
            }
            red[p][i][wave] = self;
        }
        __syncthreads();
#pragma unroll
        for (int j = 0; j < S_VECS; ++j) {
            if (j < i) d[j] += red[p][j][w1] + red[p][j][w2];
        }
        self += red[p][i][w1] + red[p][i][w2];
        inv_n[i - 1] = 1.0f / self;

#pragma unroll
        for (int j = 0; j < S_VECS; ++j) {
            if (j < i) {
                const float proj = d[j] * inv_n[j];
#pragma unroll
                for (int e = 0; e < 4; ++e) v[i][e] -= proj * v[j][e];
            }
        }
    }
    // self-dot of the last residual
    {
        float self = 0.f;
#pragma unroll
        for (int e = 0; e < 4; ++e) self += v[S_VECS - 1][e] * v[S_VECS - 1][e];
        self = wave_reduce_sum(self);
        if (lane == 0) red[0][0][wave] = self;
        __syncthreads();
        self += red[0][0][w1] + red[0][0][w2];
        inv_n[S_VECS - 1] = 1.0f / self;
    }

    // store with deferred normalization — PLAIN writeback stores
    f32x4* dst = reinterpret_cast<f32x4*>(out) + b * (S_VECS * CHUNKS);
#pragma unroll
    for (int s = 0; s < S_VECS; ++s) {
        const float inv_norm = sqrtf(inv_n[s]);  // 1/sqrt(n)
        f32x4 f;
        f.x = v[s][0] * inv_norm;
        f.y = v[s][1] * inv_norm;
        f.z = v[s][2] * inv_norm;
        f.w = v[s][3] * inv_norm;
        dst[s * CHUNKS + chunk] = f;
    }
}

__global__ __launch_bounds__(192)
void gram_schmidt_kernel(const float* __restrict__ in, float* __restrict__ out) {
    const int wave = threadIdx.x >> 6;   // 0..2
    const int lane = threadIdx.x & 63;
    const int chunk = wave * 64 + lane;  // 0..191

    __shared__ float red[2][S_VECS][3];  // [parity][value][wave]
    const int w1 = (wave == 2) ? 0 : wave + 1;
    const int w2 = (wave == 0) ? 2 : wave - 1;

    const size_t bA = (size_t)blockIdx.x * 2;
    const size_t bB = bA + 1;

    // ---- issue ALL loads for both batches up-front (cross-batch MLP) ----
    float vA[S_VECS][4], vB[S_VECS][4];
    const f32x4* srcA = reinterpret_cast<const f32x4*>(in) + bA * (S_VECS * CHUNKS);
    const f32x4* srcB = reinterpret_cast<const f32x4*>(in) + bB * (S_VECS * CHUNKS);
#pragma unroll
    for (int s = 0; s < S_VECS; ++s) {
        f32x4 f = srcA[s * CHUNKS + chunk];
        vA[s][0] = f.x; vA[s][1] = f.y; vA[s][2] = f.z; vA[s][3] = f.w;
    }
#pragma unroll
    for (int s = 0; s < S_VECS; ++s) {
        f32x4 f = srcB[s * CHUNKS + chunk];
        vB[s][0] = f.x; vB[s][1] = f.y; vB[s][2] = f.z; vB[s][3] = f.w;
    }

    process_store(vA, red, wave, lane, w1, w2, out, bA, chunk);
    process_store(vB, red, wave, lane, w1, w2, out, bB, chunk);
}

extern "C" void kernel_launch(void* const* d_in, const int* in_sizes, int n_in,
                              void* d_out, int out_size, void* d_ws, size_t ws_size,
                              hipStream_t stream) {
    const float* in = (const float*)d_in[0];
    float* out = (float*)d_out;
    const int B = in_sizes[0] / (S_VECS * D_DIM);  // 4096
    gram_schmidt_kernel<<<B / 2, 192, 0, stream>>>(in, out);
}

// Round 7
// 45.852 us; speedup vs baseline: 1.0807x; 1.0807x over previous
//
#include <hip/hip_runtime.h>

// Batched Gram-Schmidt with TRUE two-batch interleaving:
// two independent batches (A,B) fused phase-by-phase in one 192-thread block.
// While A's 6-deep shuffle-reduce chains drain, B's dot FMAs issue (and vice
// versa) — 2(i+1) independent reduction chains pipelined per phase, ONE
// shared barrier per phase. R6 failed because the compiler sank B's loads
// past A's compute (VGPR=52 proved it); here B's phase-i results are consumed
// between A's phases, forcing both register sets live (expect VGPR ~120).

#define S_VECS 8
#define CHUNKS 192  // float4 chunks per vector (768/4)

typedef float f32x4 __attribute__((ext_vector_type(4)));

__device__ __forceinline__ float wave_reduce_sum(float x) {
#pragma unroll
    for (int off = 32; off >= 1; off >>= 1)
        x += __shfl_xor(x, off, 64);
    return x;
}

__global__ __launch_bounds__(192)
void gram_schmidt_kernel(const float* __restrict__ in, float* __restrict__ out) {
    const int wave = threadIdx.x >> 6;   // 0..2
    const int lane = threadIdx.x & 63;
    const int chunk = wave * 64 + lane;  // 0..191

    __shared__ float red[2][2][S_VECS][3];  // [parity][batch][value][wave]
    const int w1 = (wave == 2) ? 0 : wave + 1;
    const int w2 = (wave == 0) ? 2 : wave - 1;

    const size_t bA = (size_t)blockIdx.x * 2;
    const size_t bB = bA + 1;

    // ---- issue all 16 loads up-front ----
    float vA[S_VECS][4], vB[S_VECS][4];
    const f32x4* srcA = reinterpret_cast<const f32x4*>(in) + bA * (S_VECS * CHUNKS);
    const f32x4* srcB = reinterpret_cast<const f32x4*>(in) + bB * (S_VECS * CHUNKS);
#pragma unroll
    for (int s = 0; s < S_VECS; ++s) {
        f32x4 fa = srcA[s * CHUNKS + chunk];
        f32x4 fb = srcB[s * CHUNKS + chunk];
        vA[s][0] = fa.x; vA[s][1] = fa.y; vA[s][2] = fa.z; vA[s][3] = fa.w;
        vB[s][0] = fb.x; vB[s][1] = fb.y; vB[s][2] = fb.z; vB[s][3] = fb.w;
    }

    float inv_nA[S_VECS], inv_nB[S_VECS];

#pragma unroll
    for (int i = 1; i < S_VECS; ++i) {
        const int p = i & 1;

        // --- partial dots for BOTH batches (2i+2 independent FMA chains) ---
        float dA[S_VECS], dB[S_VECS];
#pragma unroll
        for (int j = 0; j < S_VECS; ++j) {
            if (j < i) {
                float a = 0.f, b2 = 0.f;
#pragma unroll
                for (int e = 0; e < 4; ++e) {
                    a += vA[i][e] * vA[j][e];
                    b2 += vB[i][e] * vB[j][e];
                }
                dA[j] = a; dB[j] = b2;
            }
        }
        float selfA = 0.f, selfB = 0.f;
#pragma unroll
        for (int e = 0; e < 4; ++e) {
            selfA += vA[i - 1][e] * vA[i - 1][e];
            selfB += vB[i - 1][e] * vB[i - 1][e];
        }

        // --- 2(i+1) independent shuffle-reduce chains, pipelined ---
#pragma unroll
        for (int j = 0; j < S_VECS; ++j) {
            if (j < i) { dA[j] = wave_reduce_sum(dA[j]); dB[j] = wave_reduce_sum(dB[j]); }
        }
        selfA = wave_reduce_sum(selfA);
        selfB = wave_reduce_sum(selfB);

        // --- cross-wave combine: ONE barrier for both batches ---
        if (lane == 0) {
#pragma unroll
            for (int j = 0; j < S_VECS; ++j) {
                if (j < i) { red[p][0][j][wave] = dA[j]; red[p][1][j][wave] = dB[j]; }
            }
            red[p][0][i][wave] = selfA;
            red[p][1][i][wave] = selfB;
        }
        __syncthreads();
#pragma unroll
        for (int j = 0; j < S_VECS; ++j) {
            if (j < i) {
                dA[j] += red[p][0][j][w1] + red[p][0][j][w2];
                dB[j] += red[p][1][j][w1] + red[p][1][j][w2];
            }
        }
        selfA += red[p][0][i][w1] + red[p][0][i][w2];
        selfB += red[p][1][i][w1] + red[p][1][i][w2];
        inv_nA[i - 1] = 1.0f / selfA;
        inv_nB[i - 1] = 1.0f / selfB;

        // --- fused multi-axpy for both batches ---
#pragma unroll
        for (int j = 0; j < S_VECS; ++j) {
            if (j < i) {
                const float pA = dA[j] * inv_nA[j];
                const float pB = dB[j] * inv_nB[j];
#pragma unroll
                for (int e = 0; e < 4; ++e) {
                    vA[i][e] -= pA * vA[j][e];
                    vB[i][e] -= pB * vB[j][e];
                }
            }
        }
    }

    // ---- self-dot of the last residuals ----
    {
        float selfA = 0.f, selfB = 0.f;
#pragma unroll
        for (int e = 0; e < 4; ++e) {
            selfA += vA[S_VECS - 1][e] * vA[S_VECS - 1][e];
            selfB += vB[S_VECS - 1][e] * vB[S_VECS - 1][e];
        }
        selfA = wave_reduce_sum(selfA);
        selfB = wave_reduce_sum(selfB);
        if (lane == 0) { red[0][0][0][wave] = selfA; red[0][1][0][wave] = selfB; }
        __syncthreads();
        selfA += red[0][0][0][w1] + red[0][0][0][w2];
        selfB += red[0][1][0][w1] + red[0][1][0][w2];
        inv_nA[S_VECS - 1] = 1.0f / selfA;
        inv_nB[S_VECS - 1] = 1.0f / selfB;
    }

    // ---- stores with deferred normalization, nontemporal ----
    f32x4* dstA = reinterpret_cast<f32x4*>(out) + bA * (S_VECS * CHUNKS);
    f32x4* dstB = reinterpret_cast<f32x4*>(out) + bB * (S_VECS * CHUNKS);
#pragma unroll
    for (int s = 0; s < S_VECS; ++s) {
        const float inA = sqrtf(inv_nA[s]);
        const float inB = sqrtf(inv_nB[s]);
        f32x4 fa, fb;
        fa.x = vA[s][0] * inA; fa.y = vA[s][1] * inA;
        fa.z = vA[s][2] * inA; fa.w = vA[s][3] * inA;
        fb.x = vB[s][0] * inB; fb.y = vB[s][1] * inB;
        fb.z = vB[s][2] * inB; fb.w = vB[s][3] * inB;
        __builtin_nontemporal_store(fa, &dstA[s * CHUNKS + chunk]);
        __builtin_nontemporal_store(fb, &dstB[s * CHUNKS + chunk]);
    }
}

extern "C" void kernel_launch(void* const* d_in, const int* in_sizes, int n_in,
                              void* d_out, int out_size, void* d_ws, size_t ws_size,
                              hipStream_t stream) {
    const float* in = (const float*)d_in[0];
    float* out = (float*)d_out;
    const int B = in_sizes[0] / (S_VECS * 768);  // 4096
    gram_schmidt_kernel<<<B / 2, 192, 0, stream>>>(in, out);
}